// Round 5
// baseline (692.633 us; speedup 1.0000x reference)
//
#include <hip/hip_runtime.h>
#include <stdint.h>

#define B_   32
#define L_   512
#define DT_  4
#define NT_  20
#define SMP_ 50
#define H_   132
#define HPAD 144      // 9 n-tiles of 16
#define KSTR 168      // LDS k-stride (bf16) for W rows: breaks bank conflicts, keeps 16B align
#define KCH  5        // 5 k-chunks of 32 (K padded 132 -> 160)
#define NTIL 9

typedef float  float4v __attribute__((ext_vector_type(4)));
typedef short  short8  __attribute__((ext_vector_type(8)));

// ---------------- threefry2x32, key=(0,42), JAX partitionable 32-bit path ------------
// bits[f] = o0 ^ o1 of threefry2x32((0,42), ctr=(f>>32, f)) ; f < 2^32 here.
// R0 tested o1 only, R2 tested o0 / swapped-ctr o1, R1 tested legacy concat,
// R3 tested numpy PCG64 -- all failed at the wrong-noise extreme-value band
// (0.031-0.039). The actual JAX partitionable combine for bit_width=32 is
// convert(bits1 ^ bits2) -- the XOR of both output words (jax/_src/prng.py).
__device__ __forceinline__ uint32_t rotl32(uint32_t x, uint32_t r){ return (x<<r)|(x>>(32u-r)); }

__device__ __forceinline__ float tf_uniform_xor(uint32_t f){
  const uint32_t ks1 = 42u;
  const uint32_t ks2 = 0x1BD11BDAu ^ 42u;
  uint32_t x0 = 0u;          // ctr_hi + ks0 (both 0)
  uint32_t x1 = f + ks1;     // ctr_lo + ks1
  // group 0: 13,15,26,6
  x0+=x1; x1=rotl32(x1,13); x1^=x0;
  x0+=x1; x1=rotl32(x1,15); x1^=x0;
  x0+=x1; x1=rotl32(x1,26); x1^=x0;
  x0+=x1; x1=rotl32(x1, 6); x1^=x0;
  x0+=ks1; x1+=ks2+1u;
  // group 1: 17,29,16,24
  x0+=x1; x1=rotl32(x1,17); x1^=x0;
  x0+=x1; x1=rotl32(x1,29); x1^=x0;
  x0+=x1; x1=rotl32(x1,16); x1^=x0;
  x0+=x1; x1=rotl32(x1,24); x1^=x0;
  x0+=ks2; x1+=2u;                  // ks0+2
  // group 2: 13,15,26,6
  x0+=x1; x1=rotl32(x1,13); x1^=x0;
  x0+=x1; x1=rotl32(x1,15); x1^=x0;
  x0+=x1; x1=rotl32(x1,26); x1^=x0;
  x0+=x1; x1=rotl32(x1, 6); x1^=x0;
  /*x0+=ks0*/ x1+=ks1+3u;
  // group 3: 17,29,16,24
  x0+=x1; x1=rotl32(x1,17); x1^=x0;
  x0+=x1; x1=rotl32(x1,29); x1^=x0;
  x0+=x1; x1=rotl32(x1,16); x1^=x0;
  x0+=x1; x1=rotl32(x1,24); x1^=x0;
  x0+=ks1; x1+=ks2+4u;
  // group 4: 13,15,26,6
  x0+=x1; x1=rotl32(x1,13); x1^=x0;
  x0+=x1; x1=rotl32(x1,15); x1^=x0;
  x0+=x1; x1=rotl32(x1,26); x1^=x0;
  x0+=x1; x1=rotl32(x1, 6); x1^=x0;
  x0+=ks2; x1+=5u;                  // ks0+5
  uint32_t b = x0 ^ x1;             // partitionable 32-bit combine
  return __uint_as_float((b>>9) | 0x3f800000u) - 1.0f;
}

__device__ __forceinline__ float softplus_f(float x){
  return fmaxf(x,0.f) + log1pf(expf(-fabsf(x)));
}

__device__ __forceinline__ short f2bf(float f){   // fp32 -> bf16 RNE
  uint32_t u = __float_as_uint(f);
  u += 0x7fffu + ((u>>16)&1u);
  return (short)(u>>16);
}

// ---------------- K0: embeddings + per-event scalars + zero mean output ----------------
__global__ __launch_bounds__(64) void k0_embed(
    const int* __restrict__ etype, const float* __restrict__ etime,
    const float* __restrict__ Wt,  const float* __restrict__ temb,
    const float* __restrict__ Wg,  const float* __restrict__ Wl,
    float* __restrict__ hv, float* __restrict__ sc4, float* __restrict__ outmean){
  int bl = blockIdx.x;
  int l  = bl & (L_-1);
  int k  = threadIdx.x;                 // 0..63
  float t = etime[bl];
  const float M = -0.07195578414202429f;  // -ln(10000)/128
  float dterm = expf((float)(2*k) * M);
  float ang = (float)l * dterm + t * Wt[k];
  float sv, cv;
  sincosf(ang, &sv, &cv);
  hv[(size_t)bl*H_ + k]      = sv;
  hv[(size_t)bl*H_ + 64 + k] = cv;
  int et = etype[bl];
  if (k < 4) hv[(size_t)bl*H_ + 128 + k] = temb[et*4 + k];
  if (k == 0){
    float t0 = temb[et*4+0], t1 = temb[et*4+1], t2 = temb[et*4+2], t3 = temb[et*4+3];
    sc4[bl*4+0] = t0*Wg[0]+t1*Wg[1]+t2*Wg[2]+t3*Wg[3];  // dg  (j-side)
    sc4[bl*4+1] = t0*Wg[4]+t1*Wg[5]+t2*Wg[6]+t3*Wg[7];  // dg2 (i-side)
    sc4[bl*4+2] = t0*Wl[0]+t1*Wl[1]+t2*Wl[2]+t3*Wl[3];  // dl
    sc4[bl*4+3] = t0*Wl[4]+t1*Wl[5]+t2*Wl[6]+t3*Wl[7];  // dl2
    outmean[bl] = 0.f;   // zero accumulator for K4 atomics (out is poisoned 0xAA)
  }
}

// ---------------- K1: gated-kernel attention (scores + aggregate) ----------------
__global__ __launch_bounds__(256) void k1_attn(
    const float* __restrict__ etime, const float* __restrict__ sc4,
    const float* __restrict__ hv, const float* __restrict__ bgp, const float* __restrict__ blp,
    float* __restrict__ hidden){
  __shared__ float sc[L_];
  int i = blockIdx.x, b = blockIdx.y;
  int base = b*L_;
  float ti   = etime[base+i];
  float dg2i = sc4[(base+i)*4+1];
  float dl2i = sc4[(base+i)*4+3];
  float bg = bgp[0], blv = blp[0];
  for (int j = threadIdx.x; j < L_; j += 256){
    float v = 0.f;
    if (j < i){   // strictly lower triangle (tril k=-1)
      float tj   = etime[base+j];
      float gate = 1.f/(1.f+expf(-(sc4[(base+j)*4+0] + dg2i + bg)));
      float ls   = softplus_f(sc4[(base+j)*4+2] + dl2i + blv) + 1e-6f;
      float d    = ti - tj;
      v = gate / (1.f + d*d/(2.f*ls*ls));
    }
    sc[j] = v;
  }
  __syncthreads();
  int h = threadIdx.x;
  if (h < H_){
    float acc = 0.f;
    const float* hvb = hv + (size_t)base*H_ + h;
    #pragma unroll 4
    for (int j = 0; j < i; ++j) acc += sc[j] * hvb[(size_t)j*H_];
    hidden[(size_t)(base+i)*H_ + h] = acc;
  }
}

// ---------------- K2: LayerNorm (one wave per row) ----------------
__global__ __launch_bounds__(64) void k2_ln(
    const float* __restrict__ hidden, const float* __restrict__ gamma,
    const float* __restrict__ beta, float* __restrict__ hn){
  int bl = blockIdx.x, lane = threadIdx.x;
  const float* row = hidden + (size_t)bl*H_;
  float x0 = row[lane], x1 = row[64+lane];
  float x2 = (lane<4) ? row[128+lane] : 0.f;
  float sum = x0+x1+x2;
  #pragma unroll
  for (int m=32; m; m>>=1) sum += __shfl_xor(sum, m, 64);
  float mu = sum * (1.f/132.f);
  float d0=x0-mu, d1=x1-mu, d2=(lane<4)?(x2-mu):0.f;
  float vs = d0*d0+d1*d1+d2*d2;
  #pragma unroll
  for (int m=32; m; m>>=1) vs += __shfl_xor(vs, m, 64);
  float rn = rsqrtf(vs*(1.f/132.f) + 1e-6f);
  float* o = hn + (size_t)bl*H_;
  o[lane]    = d0*rn*gamma[lane]    + beta[lane];
  o[64+lane] = d1*rn*gamma[64+lane] + beta[64+lane];
  if (lane<4) o[128+lane] = d2*rn*gamma[128+lane] + beta[128+lane];
}

// ---------------- K3: decoder prep: c = hn@W_in^T ; mark_probs = softmax(hn@W_pred^T) ----------------
#define ROWS 64
__global__ __launch_bounds__(256) void k3_dec(
    const float* __restrict__ hn, const float* __restrict__ Win,
    const float* __restrict__ Wpred, float* __restrict__ cvec, float* __restrict__ outp){
  __shared__ __align__(16) float hnT[H_*ROWS];   // [k][r]
  __shared__ float logit[ROWS*NT_];
  int row0 = blockIdx.x * ROWS;
  for (int e = threadIdx.x; e < ROWS*H_; e += 256){
    int r = e / H_; int k = e - r*H_;
    hnT[k*ROWS + r] = hn[(size_t)(row0+r)*H_ + k];
  }
  __syncthreads();
  int t = threadIdx.x;
  if (t < H_+NT_){
    const float* wr = (t < H_) ? (Win + (size_t)t*H_) : (Wpred + (size_t)(t-H_)*H_);
    for (int rc = 0; rc < 4; ++rc){
      float acc[16];
      #pragma unroll
      for (int r=0;r<16;++r) acc[r]=0.f;
      for (int k = 0; k < H_; ++k){
        float w = wr[k];
        const float* hp = &hnT[k*ROWS + rc*16];
        #pragma unroll
        for (int r=0;r<16;++r) acc[r] += w * hp[r];
      }
      if (t < H_){
        #pragma unroll
        for (int r=0;r<16;++r) cvec[(size_t)(row0+rc*16+r)*H_ + t] = acc[r];
      } else {
        #pragma unroll
        for (int r=0;r<16;++r) logit[(rc*16+r)*NT_ + (t-H_)] = acc[r];
      }
    }
  }
  __syncthreads();
  if (t < ROWS){
    float mx = -1e30f;
    for (int j=0;j<NT_;++j) mx = fmaxf(mx, logit[t*NT_+j]);
    float ex[NT_]; float ssum = 0.f;
    for (int j=0;j<NT_;++j){ ex[j] = expf(logit[t*NT_+j]-mx); ssum += ex[j]; }
    float inv = 1.f/ssum;
    for (int j=0;j<NT_;++j)
      outp[(size_t)(B_*L_) + (size_t)(row0+t)*NT_ + j] = ex[j]*inv;
  }
}

// ---------------- K4: GAN sampler. bf16 MFMA GEMM + in-register threefry noise ----------------
// block = 512 thr (8 waves); wave w handles sample s = blockIdx.z*8 + w for 16 l-rows.
__global__ __launch_bounds__(512, 4) void k4_sampler(
    const float* __restrict__ Wn, const float* __restrict__ cvec,
    const float* __restrict__ wt, float* __restrict__ outmean){
  __shared__ __align__(16) short Wlds[HPAD*KSTR];   // W_noise[n][k] bf16, zero-padded
  __shared__ __align__(16) float clds[16*HPAD];     // c[l_local][n]
  __shared__ float wtlds[HPAD];
  __shared__ float part[8*16];
  int tid = threadIdx.x;
  int l0 = blockIdx.x*16, b = blockIdx.y, sch = blockIdx.z;
  int bl0 = b*L_ + l0;

  for (int e = tid; e < HPAD*KSTR; e += 512){
    int n = e / KSTR; int k = e - n*KSTR;
    short v = 0;
    if (n < H_ && k < H_) v = f2bf(Wn[n*H_ + k]);
    Wlds[e] = v;
  }
  for (int e = tid; e < 16*HPAD; e += 512){
    int m = e / HPAD; int n = e - m*HPAD;
    clds[e] = (n < H_) ? cvec[(size_t)(bl0+m)*H_ + n] : 0.f;
  }
  if (tid < HPAD) wtlds[tid] = (tid < H_) ? wt[tid] : 0.f;
  if (tid < 128) part[tid] = 0.f;
  __syncthreads();

  int wave = tid >> 6, lane = tid & 63;
  int q = lane >> 4, col = lane & 15;
  int s = sch*8 + wave;
  if (s < SMP_){
    // A-fragments: lane holds noise[m=col][k = kc*32 + q*8 + j]  (MFMA A layout)
    short8 afr[KCH];
    uint32_t nbase = ((uint32_t)(bl0 + col)*SMP_ + (uint32_t)s)*H_;
    #pragma unroll
    for (int kc = 0; kc < KCH; ++kc){
      #pragma unroll
      for (int j = 0; j < 8; ++j){
        int k = kc*32 + q*8 + j;
        short v = 0;
        if (k < H_) v = f2bf(tf_uniform_xor(nbase + (uint32_t)k));
        afr[kc][j] = v;
      }
    }
    float racc0=0.f, racc1=0.f, racc2=0.f, racc3=0.f;
    for (int nt = 0; nt < NTIL; ++nt){
      float4v acc = {0.f,0.f,0.f,0.f};
      const short8* bp = (const short8*)&Wlds[(nt*16+col)*KSTR];
      #pragma unroll
      for (int kc = 0; kc < KCH; ++kc){
        short8 bfr = bp[kc*4 + q];    // B[k][n]: n=lane&15, k=quad*8+j
        acc = __builtin_amdgcn_mfma_f32_16x16x32_bf16(afr[kc], bfr, acc, 0, 0, 0);
      }
      int n = nt*16 + col;            // C/D: col=lane&15, row=quad*4+reg
      float wv = wtlds[n];
      racc0 += fmaxf(acc[0] + clds[(q*4+0)*HPAD + n], 0.f)*wv;
      racc1 += fmaxf(acc[1] + clds[(q*4+1)*HPAD + n], 0.f)*wv;
      racc2 += fmaxf(acc[2] + clds[(q*4+2)*HPAD + n], 0.f)*wv;
      racc3 += fmaxf(acc[3] + clds[(q*4+3)*HPAD + n], 0.f)*wv;
    }
    #pragma unroll
    for (int m = 1; m < 16; m <<= 1){
      racc0 += __shfl_xor(racc0, m, 64);
      racc1 += __shfl_xor(racc1, m, 64);
      racc2 += __shfl_xor(racc2, m, 64);
      racc3 += __shfl_xor(racc3, m, 64);
    }
    if (col == 0){
      part[wave*16 + q*4 + 0] = 0.02f * softplus_f(racc0);
      part[wave*16 + q*4 + 1] = 0.02f * softplus_f(racc1);
      part[wave*16 + q*4 + 2] = 0.02f * softplus_f(racc2);
      part[wave*16 + q*4 + 3] = 0.02f * softplus_f(racc3);
    }
  }
  __syncthreads();
  if (tid < 16){
    float v = 0.f;
    #pragma unroll
    for (int w = 0; w < 8; ++w) v += part[w*16 + tid];
    atomicAdd(&outmean[bl0 + tid], v);
  }
}

// ---------------- launch ----------------
extern "C" void kernel_launch(void* const* d_in, const int* in_sizes, int n_in,
                              void* d_out, int out_size, void* d_ws, size_t ws_size,
                              hipStream_t stream){
  const int*   etype = (const int*)  d_in[0];
  const float* etime = (const float*)d_in[1];
  const float* Wt    = (const float*)d_in[3];
  const float* temb  = (const float*)d_in[4];
  const float* Wg    = (const float*)d_in[5];
  const float* bgp   = (const float*)d_in[6];
  const float* Wl    = (const float*)d_in[7];
  const float* blp   = (const float*)d_in[8];
  const float* gamma = (const float*)d_in[9];
  const float* beta  = (const float*)d_in[10];
  const float* Win   = (const float*)d_in[11];
  const float* Wn    = (const float*)d_in[12];
  const float* wtm   = (const float*)d_in[13];
  const float* Wpred = (const float*)d_in[14];
  float* out = (float*)d_out;

  float* hv     = (float*)d_ws;                    // 16384*132
  float* sc4    = hv     + (size_t)16384*H_;       // 16384*4
  float* hidden = sc4    + (size_t)16384*4;        // 16384*132
  float* hn     = hidden + (size_t)16384*H_;       // 16384*132
  float* cvec   = hidden;                          // reuse: hidden dead after K2

  k0_embed  <<<dim3(16384),     dim3(64),  0, stream>>>(etype, etime, Wt, temb, Wg, Wl, hv, sc4, out);
  k1_attn   <<<dim3(512,32),    dim3(256), 0, stream>>>(etime, sc4, hv, bgp, blp, hidden);
  k2_ln     <<<dim3(16384),     dim3(64),  0, stream>>>(hidden, gamma, beta, hn);
  k3_dec    <<<dim3(256),       dim3(256), 0, stream>>>(hn, Win, Wpred, cvec, out);
  k4_sampler<<<dim3(32,32,7),   dim3(512), 0, stream>>>(Wn, cvec, wtm, out);
}

// Round 6
// 664.506 us; speedup vs baseline: 1.0423x; 1.0423x over previous
//
#include <hip/hip_runtime.h>
#include <stdint.h>

#define B_   32
#define L_   512
#define DT_  4
#define NT_  20
#define SMP_ 50
#define H_   132
#define HPAD 144      // 9 n-tiles of 16
#define KSTR 136      // LDS k-stride (shorts): 272B rows, 16B-aligned, 2-way-max banks (free)
#define CSTR 148      // clds float stride: breaks q*4-row bank aliasing (q stride 16 banks)
#define KCH  5        // 5 k-chunks of 32 (K padded 132 -> 160)
#define NTIL 9

typedef float  float4v __attribute__((ext_vector_type(4)));
typedef short  short8  __attribute__((ext_vector_type(8)));

// ---------------- threefry2x32, key=(0,42), JAX partitionable 32-bit path ------------
// bits[f] = o0 ^ o1 of threefry2x32((0,42), ctr=(0, f))  [verified passing in R5]
// Output here: bf16 of u2 = fp32(0x3f800000|(bits>>9)) in [1,2), RNE.
// The "-1" is folded into the C tile as -rowsum(bf16(W)) (exact cancellation).
__device__ __forceinline__ uint32_t rotl32(uint32_t x, uint32_t r){ return (x<<r)|(x>>(32u-r)); }

__device__ __forceinline__ short tf_bf16(uint32_t f){
  const uint32_t ks1 = 42u;
  const uint32_t ks2 = 0x1BD11BDAu ^ 42u;
  uint32_t x0 = 0u;          // ctr_hi + ks0 (both 0)
  uint32_t x1 = f + ks1;     // ctr_lo + ks1
  x0+=x1; x1=rotl32(x1,13); x1^=x0;
  x0+=x1; x1=rotl32(x1,15); x1^=x0;
  x0+=x1; x1=rotl32(x1,26); x1^=x0;
  x0+=x1; x1=rotl32(x1, 6); x1^=x0;
  x0+=ks1; x1+=ks2+1u;
  x0+=x1; x1=rotl32(x1,17); x1^=x0;
  x0+=x1; x1=rotl32(x1,29); x1^=x0;
  x0+=x1; x1=rotl32(x1,16); x1^=x0;
  x0+=x1; x1=rotl32(x1,24); x1^=x0;
  x0+=ks2; x1+=2u;                  // ks0+2
  x0+=x1; x1=rotl32(x1,13); x1^=x0;
  x0+=x1; x1=rotl32(x1,15); x1^=x0;
  x0+=x1; x1=rotl32(x1,26); x1^=x0;
  x0+=x1; x1=rotl32(x1, 6); x1^=x0;
  /*x0+=ks0*/ x1+=ks1+3u;
  x0+=x1; x1=rotl32(x1,17); x1^=x0;
  x0+=x1; x1=rotl32(x1,29); x1^=x0;
  x0+=x1; x1=rotl32(x1,16); x1^=x0;
  x0+=x1; x1=rotl32(x1,24); x1^=x0;
  x0+=ks1; x1+=ks2+4u;
  x0+=x1; x1=rotl32(x1,13); x1^=x0;
  x0+=x1; x1=rotl32(x1,15); x1^=x0;
  x0+=x1; x1=rotl32(x1,26); x1^=x0;
  x0+=x1; x1=rotl32(x1, 6); x1^=x0;
  x0+=ks2; x1+=5u;                  // ks0+5
  uint32_t bb = x0 ^ x1;            // partitionable 32-bit combine
  // bf16(fp32 bits 0x3f800000|(bb>>9)) with RNE: carry into exponent OK (-> 2.0)
  uint32_t Y = (bb>>9) + ((bb>>25)&1u) + 0x3f807fffu;
  return (short)(Y>>16);
}

__device__ __forceinline__ float softplus_f(float x){
  return fmaxf(x,0.f) + log1pf(expf(-fabsf(x)));
}

__device__ __forceinline__ short f2bf(float f){   // fp32 -> bf16 RNE
  uint32_t u = __float_as_uint(f);
  u += 0x7fffu + ((u>>16)&1u);
  return (short)(u>>16);
}

__device__ __forceinline__ float bf_round(float f){   // fp32 -> bf16 -> fp32
  uint32_t u = __float_as_uint(f);
  u += 0x7fffu + ((u>>16)&1u);
  u &= 0xffff0000u;
  return __uint_as_float(u);
}

// ---------------- K0: embeddings + per-event scalars + zero mean output ----------------
__global__ __launch_bounds__(64) void k0_embed(
    const int* __restrict__ etype, const float* __restrict__ etime,
    const float* __restrict__ Wt,  const float* __restrict__ temb,
    const float* __restrict__ Wg,  const float* __restrict__ Wl,
    float* __restrict__ hv, float* __restrict__ sc4, float* __restrict__ outmean){
  int bl = blockIdx.x;
  int l  = bl & (L_-1);
  int k  = threadIdx.x;                 // 0..63
  float t = etime[bl];
  const float M = -0.07195578414202429f;  // -ln(10000)/128
  float dterm = expf((float)(2*k) * M);
  float ang = (float)l * dterm + t * Wt[k];
  float sv, cv;
  sincosf(ang, &sv, &cv);
  hv[(size_t)bl*H_ + k]      = sv;
  hv[(size_t)bl*H_ + 64 + k] = cv;
  int et = etype[bl];
  if (k < 4) hv[(size_t)bl*H_ + 128 + k] = temb[et*4 + k];
  if (k == 0){
    float t0 = temb[et*4+0], t1 = temb[et*4+1], t2 = temb[et*4+2], t3 = temb[et*4+3];
    sc4[bl*4+0] = t0*Wg[0]+t1*Wg[1]+t2*Wg[2]+t3*Wg[3];  // dg  (j-side)
    sc4[bl*4+1] = t0*Wg[4]+t1*Wg[5]+t2*Wg[6]+t3*Wg[7];  // dg2 (i-side)
    sc4[bl*4+2] = t0*Wl[0]+t1*Wl[1]+t2*Wl[2]+t3*Wl[3];  // dl
    sc4[bl*4+3] = t0*Wl[4]+t1*Wl[5]+t2*Wl[6]+t3*Wl[7];  // dl2
    outmean[bl] = 0.f;   // zero accumulator for K4 atomics (out is poisoned 0xAA)
  }
}

// ---------------- K_rs: rowsum of bf16-rounded W_noise (exact -1 fold for K4) --------
__global__ __launch_bounds__(192) void k_rs(const float* __restrict__ Wn,
                                            float* __restrict__ rs){
  int t = threadIdx.x;
  if (t < H_){
    float s = 0.f;
    const float* row = Wn + (size_t)t*H_;
    #pragma unroll 4
    for (int k = 0; k < H_; ++k) s += bf_round(row[k]);
    rs[t] = s;
  }
}

// ---------------- K1: gated-kernel attention + fused LayerNorm ----------------
__global__ __launch_bounds__(256) void k1_attn(
    const float* __restrict__ etime, const float* __restrict__ sc4,
    const float* __restrict__ hv, const float* __restrict__ bgp, const float* __restrict__ blp,
    const float* __restrict__ gamma, const float* __restrict__ beta,
    float* __restrict__ hn){
  __shared__ float sc[L_];
  __shared__ float st2[2];
  int i = blockIdx.x, b = blockIdx.y;
  int base = b*L_;
  float ti   = etime[base+i];
  float dg2i = sc4[(base+i)*4+1];
  float dl2i = sc4[(base+i)*4+3];
  float bg = bgp[0], blv = blp[0];
  for (int j = threadIdx.x; j < L_; j += 256){
    float v = 0.f;
    if (j < i){   // strictly lower triangle (tril k=-1)
      float tj   = etime[base+j];
      float gate = 1.f/(1.f+expf(-(sc4[(base+j)*4+0] + dg2i + bg)));
      float ls   = softplus_f(sc4[(base+j)*4+2] + dl2i + blv) + 1e-6f;
      float d    = ti - tj;
      v = gate / (1.f + d*d/(2.f*ls*ls));
    }
    sc[j] = v;
  }
  __syncthreads();
  int h = threadIdx.x;
  float acc = 0.f;
  if (h < H_){
    const float* hvb = hv + (size_t)base*H_ + h;
    #pragma unroll 4
    for (int j = 0; j < i; ++j) acc += sc[j] * hvb[(size_t)j*H_];
  }
  __syncthreads();                 // sc no longer needed as scores
  if (h < H_) sc[h] = acc;
  __syncthreads();
  if (h < 64){
    float x0 = sc[h], x1 = sc[64+h], x2 = (h<4) ? sc[128+h] : 0.f;
    float s1 = x0+x1+x2;
    float s2 = x0*x0+x1*x1+x2*x2;
    #pragma unroll
    for (int m=32; m; m>>=1){ s1 += __shfl_xor(s1, m, 64); s2 += __shfl_xor(s2, m, 64); }
    if (h == 0){
      float mu = s1 * (1.f/132.f);
      float var = s2 * (1.f/132.f) - mu*mu;
      st2[0] = mu; st2[1] = rsqrtf(var + 1e-6f);
    }
  }
  __syncthreads();
  if (h < H_){
    float mu = st2[0], rn = st2[1];
    hn[(size_t)(base+i)*H_ + h] = (acc-mu)*rn*gamma[h] + beta[h];
  }
}

// ---------------- K3: decoder prep: c = hn@W_in^T ; mark_probs = softmax(hn@W_pred^T) ----------------
#define ROWS 64
__global__ __launch_bounds__(256) void k3_dec(
    const float* __restrict__ hn, const float* __restrict__ Win,
    const float* __restrict__ Wpred, float* __restrict__ cvec, float* __restrict__ outp){
  __shared__ __align__(16) float hnT[H_*ROWS];   // [k][r]
  __shared__ float logit[ROWS*NT_];
  int row0 = blockIdx.x * ROWS;
  for (int e = threadIdx.x; e < ROWS*H_; e += 256){
    int r = e / H_; int k = e - r*H_;
    hnT[k*ROWS + r] = hn[(size_t)(row0+r)*H_ + k];
  }
  __syncthreads();
  int t = threadIdx.x;
  if (t < H_+NT_){
    const float* wr = (t < H_) ? (Win + (size_t)t*H_) : (Wpred + (size_t)(t-H_)*H_);
    for (int rc = 0; rc < 4; ++rc){
      float acc[16];
      #pragma unroll
      for (int r=0;r<16;++r) acc[r]=0.f;
      for (int k = 0; k < H_; ++k){
        float w = wr[k];
        const float* hp = &hnT[k*ROWS + rc*16];
        #pragma unroll
        for (int r=0;r<16;++r) acc[r] += w * hp[r];
      }
      if (t < H_){
        #pragma unroll
        for (int r=0;r<16;++r) cvec[(size_t)(row0+rc*16+r)*H_ + t] = acc[r];
      } else {
        #pragma unroll
        for (int r=0;r<16;++r) logit[(rc*16+r)*NT_ + (t-H_)] = acc[r];
      }
    }
  }
  __syncthreads();
  if (t < ROWS){
    float mx = -1e30f;
    for (int j=0;j<NT_;++j) mx = fmaxf(mx, logit[t*NT_+j]);
    float ex[NT_]; float ssum = 0.f;
    for (int j=0;j<NT_;++j){ ex[j] = expf(logit[t*NT_+j]-mx); ssum += ex[j]; }
    float inv = 1.f/ssum;
    for (int j=0;j<NT_;++j)
      outp[(size_t)(B_*L_) + (size_t)(row0+t)*NT_ + j] = ex[j]*inv;
  }
}

// ---------------- K4: GAN sampler. bf16 MFMA GEMM + in-register threefry noise ----------------
// block = 512 thr (8 waves); wave w handles sample s = blockIdx.z*8 + w for 16 l-rows.
// LDS 49728 B -> 3 blocks/CU (24 waves, 75% occupancy).
__global__ __launch_bounds__(512, 6) void k4_sampler(
    const float* __restrict__ Wn, const float* __restrict__ cvec,
    const float* __restrict__ wt, const float* __restrict__ rs,
    float* __restrict__ outmean){
  __shared__ __align__(16) short Wlds[HPAD*KSTR];   // W_noise[n][k] bf16, zero-padded
  __shared__ __align__(16) float clds[16*CSTR];     // (c - rowsumW)[l_local][n]
  __shared__ float wtlds[HPAD];
  __shared__ float part[128];
  int tid = threadIdx.x, lane = tid & 63;
  int l0 = blockIdx.x*16, b = blockIdx.y, sch = blockIdx.z;
  int bl0 = b*L_ + l0;

  // stage W rows (8 rows in flight across the block; no integer div)
  for (int n = tid>>6; n < HPAD; n += 8){
    for (int k = lane; k < KSTR; k += 64){
      short v = 0;
      if (n < H_ && k < H_) v = f2bf(Wn[n*H_ + k]);
      Wlds[n*KSTR + k] = v;
    }
  }
  // stage c - rowsum(bf16(W))
  for (int m = tid>>6; m < 16; m += 8){
    for (int n = lane; n < CSTR; n += 64){
      float v = 0.f;
      if (n < H_) v = cvec[(size_t)(bl0+m)*H_ + n] - rs[n];
      clds[m*CSTR + n] = v;
    }
  }
  if (tid < HPAD) wtlds[tid] = (tid < H_) ? wt[tid] : 0.f;
  if (tid < 128) part[tid] = 0.f;
  __syncthreads();

  int wave = tid >> 6;
  int q = lane >> 4, col = lane & 15;
  int s = sch*8 + wave;
  if (s < SMP_){
    // A-fragments: lane holds noise[m=col][k = kc*32 + q*8 + j]  (MFMA A layout)
    uint32_t fbase = (uint32_t)(bl0 + col)*(uint32_t)(SMP_*H_)
                   + (uint32_t)s*(uint32_t)H_ + (uint32_t)(q*8);
    short8 afr[KCH];
    #pragma unroll
    for (int kc = 0; kc < 4; ++kc){          // k = kc*32+q*8+j <= 127 < H_: no guard
      #pragma unroll
      for (int j = 0; j < 8; ++j)
        afr[kc][j] = tf_bf16(fbase + (uint32_t)(kc*32 + j));
    }
    {   // tail chunk: only q==0, j<4 carry real k (128..131)
      short8 a4 = {0,0,0,0,0,0,0,0};
      if (q == 0){
        #pragma unroll
        for (int j = 0; j < 4; ++j)
          a4[j] = tf_bf16(fbase + (uint32_t)(128 + j));
      }
      afr[4] = a4;
    }
    float racc0=0.f, racc1=0.f, racc2=0.f, racc3=0.f;
    for (int nt = 0; nt < NTIL; ++nt){
      float4v acc = {0.f,0.f,0.f,0.f};
      const short8* bp = (const short8*)&Wlds[(nt*16+col)*KSTR];
      #pragma unroll
      for (int kc = 0; kc < KCH; ++kc){
        short8 bfr = bp[kc*4 + q];    // B[k][n]: n=lane&15, k=quad*8+j
        acc = __builtin_amdgcn_mfma_f32_16x16x32_bf16(afr[kc], bfr, acc, 0, 0, 0);
      }
      int n = nt*16 + col;            // C/D: col=lane&15, row=quad*4+reg
      float wv = wtlds[n];
      const float* cb = &clds[(q*4)*CSTR + n];
      racc0 += fmaxf(acc[0] + cb[0*CSTR], 0.f)*wv;
      racc1 += fmaxf(acc[1] + cb[1*CSTR], 0.f)*wv;
      racc2 += fmaxf(acc[2] + cb[2*CSTR], 0.f)*wv;
      racc3 += fmaxf(acc[3] + cb[3*CSTR], 0.f)*wv;
    }
    #pragma unroll
    for (int m = 1; m < 16; m <<= 1){
      racc0 += __shfl_xor(racc0, m, 64);
      racc1 += __shfl_xor(racc1, m, 64);
      racc2 += __shfl_xor(racc2, m, 64);
      racc3 += __shfl_xor(racc3, m, 64);
    }
    if (col == 0){
      part[wave*16 + q*4 + 0] = 0.02f * softplus_f(racc0);
      part[wave*16 + q*4 + 1] = 0.02f * softplus_f(racc1);
      part[wave*16 + q*4 + 2] = 0.02f * softplus_f(racc2);
      part[wave*16 + q*4 + 3] = 0.02f * softplus_f(racc3);
    }
  }
  __syncthreads();
  if (tid < 16){
    float v = 0.f;
    #pragma unroll
    for (int w = 0; w < 8; ++w) v += part[w*16 + tid];
    atomicAdd(&outmean[bl0 + tid], v);
  }
}

// ---------------- launch ----------------
extern "C" void kernel_launch(void* const* d_in, const int* in_sizes, int n_in,
                              void* d_out, int out_size, void* d_ws, size_t ws_size,
                              hipStream_t stream){
  const int*   etype = (const int*)  d_in[0];
  const float* etime = (const float*)d_in[1];
  const float* Wt    = (const float*)d_in[3];
  const float* temb  = (const float*)d_in[4];
  const float* Wg    = (const float*)d_in[5];
  const float* bgp   = (const float*)d_in[6];
  const float* Wl    = (const float*)d_in[7];
  const float* blp   = (const float*)d_in[8];
  const float* gamma = (const float*)d_in[9];
  const float* beta  = (const float*)d_in[10];
  const float* Win   = (const float*)d_in[11];
  const float* Wn    = (const float*)d_in[12];
  const float* wtm   = (const float*)d_in[13];
  const float* Wpred = (const float*)d_in[14];
  float* out = (float*)d_out;

  float* hv     = (float*)d_ws;                    // 16384*132
  float* sc4    = hv     + (size_t)16384*H_;       // 16384*4
  float* hidden = sc4    + (size_t)16384*4;        // 16384*132 (cvec)
  float* hn     = hidden + (size_t)16384*H_;       // 16384*132
  float* rs     = hn     + (size_t)16384*H_;       // 132
  float* cvec   = hidden;

  k0_embed  <<<dim3(16384),     dim3(64),  0, stream>>>(etype, etime, Wt, temb, Wg, Wl, hv, sc4, out);
  k_rs      <<<dim3(1),         dim3(192), 0, stream>>>(Wn, rs);
  k1_attn   <<<dim3(512,32),    dim3(256), 0, stream>>>(etime, sc4, hv, bgp, blp, gamma, beta, hn);
  k3_dec    <<<dim3(256),       dim3(256), 0, stream>>>(hn, Win, Wpred, cvec, out);
  k4_sampler<<<dim3(32,32,7),   dim3(512), 0, stream>>>(Wn, cvec, wtm, rs, out);
}

// Round 7
// 560.708 us; speedup vs baseline: 1.2353x; 1.1851x over previous
//
#include <hip/hip_runtime.h>
#include <stdint.h>

#define B_   32
#define L_   512
#define DT_  4
#define NT_  20
#define SMP_ 50
#define H_   132
#define HPAD 144      // 9 n-tiles of 16
#define KSTR 136      // LDS k-stride (shorts): 272B rows, 16B-aligned
#define CSTR 148      // clds float stride
#define KCH  5        // 5 k-chunks of 32 (K padded 132 -> 160)
#define NTIL 9
#define WBF_N (HPAD*KSTR)      // 19584 shorts = 2448 uint4

typedef float  float4v __attribute__((ext_vector_type(4)));
typedef short  short8  __attribute__((ext_vector_type(8)));
typedef unsigned int uint4v __attribute__((ext_vector_type(4)));

#if __has_builtin(__builtin_amdgcn_alignbit)
#define ROTL(x,r) __builtin_amdgcn_alignbit((x),(x),32u-(r))
#else
#define ROTL(x,r) (((x)<<(r))|((x)>>(32u-(r))))
#endif

// ---------------- threefry2x32, key=(0,42), JAX partitionable 32-bit path ------------
// bits[f] = o0 ^ o1 of threefry2x32((0,42), ctr=(0,f))  [verified passing R5/R6]
// tfpair: TWO independent chains interleaved (ILP-2), emits packed bf16 pair
// (elem fa -> low16, fb -> high16) of 1+u in [1,2); "-1" folded via rowsum(bf16 W).
// Rounding: round-half-up (RNE tiebreak dropped: ties are 2^-16/elem, <=1e-6 on out).
__device__ __forceinline__ uint32_t tfpair(uint32_t fa, uint32_t fb){
  const uint32_t ks1 = 42u;
  const uint32_t ks2 = 0x1BD11BDAu ^ 42u;
  uint32_t a0 = 0u, b0 = 0u, a1 = fa + ks1, b1 = fb + ks1;
#define TFR(r) a0+=a1; b0+=b1; a1=ROTL(a1,(r)); b1=ROTL(b1,(r)); a1^=a0; b1^=b0;
  TFR(13) TFR(15) TFR(26) TFR(6)
  a0+=ks1; a1+=ks2+1u; b0+=ks1; b1+=ks2+1u;
  TFR(17) TFR(29) TFR(16) TFR(24)
  a0+=ks2; a1+=2u;     b0+=ks2; b1+=2u;       // ks0+2
  TFR(13) TFR(15) TFR(26) TFR(6)
  a1+=ks1+3u;          b1+=ks1+3u;            // x0+=ks0 (0)
  TFR(17) TFR(29) TFR(16) TFR(24)
  a0+=ks1; a1+=ks2+4u; b0+=ks1; b1+=ks2+4u;
  TFR(13) TFR(15) TFR(26) TFR(6)
  a0+=ks2; a1+=5u;     b0+=ks2; b1+=5u;       // ks0+5
#undef TFR
  uint32_t Ya = ((a0 ^ a1) >> 9) + 0x3f808000u;   // bf16 bits in [31:16], RHU rounding
  uint32_t Yb = ((b0 ^ b1) >> 9) + 0x3f808000u;
#if __has_builtin(__builtin_amdgcn_perm)
  return __builtin_amdgcn_perm(Ya, Yb, 0x03020706u);  // {Yb.hi16, Ya.hi16}
#else
  return (Yb & 0xffff0000u) | (Ya >> 16);
#endif
}

__device__ __forceinline__ float softplus_f(float x){
  return fmaxf(x,0.f) + log1pf(expf(-fabsf(x)));
}

__device__ __forceinline__ short f2bf(float f){   // fp32 -> bf16 RNE
  uint32_t u = __float_as_uint(f);
  u += 0x7fffu + ((u>>16)&1u);
  return (short)(u>>16);
}

__device__ __forceinline__ float bf_round(float f){   // fp32 -> bf16 -> fp32
  uint32_t u = __float_as_uint(f);
  u += 0x7fffu + ((u>>16)&1u);
  u &= 0xffff0000u;
  return __uint_as_float(u);
}

// ---------------- K0: embeddings + per-event scalars + zero mean output ----------------
__global__ __launch_bounds__(64) void k0_embed(
    const int* __restrict__ etype, const float* __restrict__ etime,
    const float* __restrict__ Wt,  const float* __restrict__ temb,
    const float* __restrict__ Wg,  const float* __restrict__ Wl,
    float* __restrict__ hv, float* __restrict__ sc4, float* __restrict__ outmean){
  int bl = blockIdx.x;
  int l  = bl & (L_-1);
  int k  = threadIdx.x;                 // 0..63
  float t = etime[bl];
  const float M = -0.07195578414202429f;  // -ln(10000)/128
  float dterm = expf((float)(2*k) * M);
  float ang = (float)l * dterm + t * Wt[k];
  float sv, cv;
  sincosf(ang, &sv, &cv);
  hv[(size_t)bl*H_ + k]      = sv;
  hv[(size_t)bl*H_ + 64 + k] = cv;
  int et = etype[bl];
  if (k < 4) hv[(size_t)bl*H_ + 128 + k] = temb[et*4 + k];
  if (k == 0){
    float t0 = temb[et*4+0], t1 = temb[et*4+1], t2 = temb[et*4+2], t3 = temb[et*4+3];
    sc4[bl*4+0] = t0*Wg[0]+t1*Wg[1]+t2*Wg[2]+t3*Wg[3];  // dg  (j-side)
    sc4[bl*4+1] = t0*Wg[4]+t1*Wg[5]+t2*Wg[6]+t3*Wg[7];  // dg2 (i-side)
    sc4[bl*4+2] = t0*Wl[0]+t1*Wl[1]+t2*Wl[2]+t3*Wl[3];  // dl
    sc4[bl*4+3] = t0*Wl[4]+t1*Wl[5]+t2*Wl[6]+t3*Wl[7];  // dl2
    outmean[bl] = 0.f;   // zero accumulator for K4 atomics (out is poisoned 0xAA)
  }
}

// ---------------- K_prep: bf16(W_noise) staged once + rowsum fold ----------------
// block r handles rows 16r..16r+15 of the padded [HPAD][KSTR] bf16 image.
__global__ __launch_bounds__(256) void k_prep(const float* __restrict__ Wn,
                                              uint16_t* __restrict__ wbf,
                                              float* __restrict__ rs){
  int blk = blockIdx.x, tid = threadIdx.x;
  for (int e = tid; e < 16*KSTR; e += 256){
    int r = e / KSTR, k = e - r*KSTR;
    int n = blk*16 + r;
    uint16_t v = 0;
    if (n < H_ && k < H_) v = (uint16_t)f2bf(Wn[n*H_ + k]);
    wbf[n*KSTR + k] = v;
  }
  if (tid < 16){
    int n = blk*16 + tid;
    if (n < H_){
      float s = 0.f;
      const float* row = Wn + (size_t)n*H_;
      #pragma unroll 4
      for (int k = 0; k < H_; ++k) s += bf_round(row[k]);
      rs[n] = s;
    }
  }
}

// ---------------- K1: gated-kernel attention + fused LayerNorm ----------------
__global__ __launch_bounds__(256) void k1_attn(
    const float* __restrict__ etime, const float* __restrict__ sc4,
    const float* __restrict__ hv, const float* __restrict__ bgp, const float* __restrict__ blp,
    const float* __restrict__ gamma, const float* __restrict__ beta,
    float* __restrict__ hn){
  __shared__ float sc[L_];
  __shared__ float st2[2];
  int i = blockIdx.x, b = blockIdx.y;
  int base = b*L_;
  float ti   = etime[base+i];
  float dg2i = sc4[(base+i)*4+1];
  float dl2i = sc4[(base+i)*4+3];
  float bg = bgp[0], blv = blp[0];
  for (int j = threadIdx.x; j < L_; j += 256){
    float v = 0.f;
    if (j < i){   // strictly lower triangle (tril k=-1)
      float tj   = etime[base+j];
      float gate = 1.f/(1.f+expf(-(sc4[(base+j)*4+0] + dg2i + bg)));
      float ls   = softplus_f(sc4[(base+j)*4+2] + dl2i + blv) + 1e-6f;
      float d    = ti - tj;
      v = gate / (1.f + d*d/(2.f*ls*ls));
    }
    sc[j] = v;
  }
  __syncthreads();
  int h = threadIdx.x;
  float acc = 0.f;
  if (h < H_){
    const float* hvb = hv + (size_t)base*H_ + h;
    #pragma unroll 4
    for (int j = 0; j < i; ++j) acc += sc[j] * hvb[(size_t)j*H_];
  }
  __syncthreads();                 // sc no longer needed as scores
  if (h < H_) sc[h] = acc;
  __syncthreads();
  if (h < 64){
    float x0 = sc[h], x1 = sc[64+h], x2 = (h<4) ? sc[128+h] : 0.f;
    float s1 = x0+x1+x2;
    float s2 = x0*x0+x1*x1+x2*x2;
    #pragma unroll
    for (int m=32; m; m>>=1){ s1 += __shfl_xor(s1, m, 64); s2 += __shfl_xor(s2, m, 64); }
    if (h == 0){
      float mu = s1 * (1.f/132.f);
      float var = s2 * (1.f/132.f) - mu*mu;
      st2[0] = mu; st2[1] = rsqrtf(var + 1e-6f);
    }
  }
  __syncthreads();
  if (h < H_){
    float mu = st2[0], rn = st2[1];
    hn[(size_t)(base+i)*H_ + h] = (acc-mu)*rn*gamma[h] + beta[h];
  }
}

// ---------------- K3: decoder prep: c = hn@W_in^T ; mark_probs = softmax(hn@W_pred^T) ----------------
#define ROWS 64
__global__ __launch_bounds__(256) void k3_dec(
    const float* __restrict__ hn, const float* __restrict__ Win,
    const float* __restrict__ Wpred, float* __restrict__ cvec, float* __restrict__ outp){
  __shared__ __align__(16) float hnT[H_*ROWS];   // [k][r]
  __shared__ float logit[ROWS*NT_];
  int row0 = blockIdx.x * ROWS;
  for (int e = threadIdx.x; e < ROWS*H_; e += 256){
    int r = e / H_; int k = e - r*H_;
    hnT[k*ROWS + r] = hn[(size_t)(row0+r)*H_ + k];
  }
  __syncthreads();
  int t = threadIdx.x;
  if (t < H_+NT_){
    const float* wr = (t < H_) ? (Win + (size_t)t*H_) : (Wpred + (size_t)(t-H_)*H_);
    for (int rc = 0; rc < 4; ++rc){
      float acc[16];
      #pragma unroll
      for (int r=0;r<16;++r) acc[r]=0.f;
      for (int k = 0; k < H_; ++k){
        float w = wr[k];
        const float* hp = &hnT[k*ROWS + rc*16];
        #pragma unroll
        for (int r=0;r<16;++r) acc[r] += w * hp[r];
      }
      if (t < H_){
        #pragma unroll
        for (int r=0;r<16;++r) cvec[(size_t)(row0+rc*16+r)*H_ + t] = acc[r];
      } else {
        #pragma unroll
        for (int r=0;r<16;++r) logit[(rc*16+r)*NT_ + (t-H_)] = acc[r];
      }
    }
  }
  __syncthreads();
  if (t < ROWS){
    float mx = -1e30f;
    for (int j=0;j<NT_;++j) mx = fmaxf(mx, logit[t*NT_+j]);
    float ex[NT_]; float ssum = 0.f;
    for (int j=0;j<NT_;++j){ ex[j] = expf(logit[t*NT_+j]-mx); ssum += ex[j]; }
    float inv = 1.f/ssum;
    for (int j=0;j<NT_;++j)
      outp[(size_t)(B_*L_) + (size_t)(row0+t)*NT_ + j] = ex[j]*inv;
  }
}

// ---------------- K4: GAN sampler. bf16 MFMA GEMM + in-register threefry noise ----------------
// block = 512 thr (8 waves); wave w handles sample s = blockIdx.z*8 + w for 16 l-rows.
// LDS 49728 B -> 3 blocks/CU. W comes pre-bf16-converted (k_prep) -> flat uint4 copy.
__global__ __launch_bounds__(512, 6) void k4_sampler(
    const uint16_t* __restrict__ wbf, const float* __restrict__ cvec,
    const float* __restrict__ wt, const float* __restrict__ rs,
    float* __restrict__ outmean){
  __shared__ __align__(16) short Wlds[WBF_N];       // W_noise[n][k] bf16, zero-padded
  __shared__ __align__(16) float clds[16*CSTR];     // (c - rowsumW)[l_local][n]
  __shared__ float wtlds[HPAD];
  __shared__ float part[128];
  int tid = threadIdx.x, lane = tid & 63;
  int l0 = blockIdx.x*16, b = blockIdx.y, sch = blockIdx.z;
  int bl0 = b*L_ + l0;

  {   // stage W: flat 2448 x 16B vector copy (pre-converted bf16 image)
    const uint4v* g = (const uint4v*)wbf;
    uint4v* l = (uint4v*)Wlds;
    for (int idx = tid; idx < WBF_N/8; idx += 512) l[idx] = g[idx];
  }
  // stage c - rowsum(bf16(W))
  for (int m = tid>>6; m < 16; m += 8){
    for (int n = lane; n < CSTR; n += 64){
      float v = 0.f;
      if (n < H_) v = cvec[(size_t)(bl0+m)*H_ + n] - rs[n];
      clds[m*CSTR + n] = v;
    }
  }
  if (tid < HPAD) wtlds[tid] = (tid < H_) ? wt[tid] : 0.f;
  if (tid < 128) part[tid] = 0.f;
  __syncthreads();

  int wave = tid >> 6;
  int q = lane >> 4, col = lane & 15;
  int s = sch*8 + wave;
  if (s < SMP_){
    // A-fragments: lane holds noise[m=col][k = kc*32 + q*8 + j]  (MFMA A layout)
    uint32_t fbase = (uint32_t)(bl0 + col)*(uint32_t)(SMP_*H_)
                   + (uint32_t)s*(uint32_t)H_ + (uint32_t)(q*8);
    uint4v afu[KCH];
    #pragma unroll
    for (int kc = 0; kc < 4; ++kc){          // k = kc*32+q*8+j <= 127 < H_: no guard
      #pragma unroll
      for (int t = 0; t < 4; ++t)
        afu[kc][t] = tfpair(fbase + (uint32_t)(kc*32 + 2*t),
                            fbase + (uint32_t)(kc*32 + 2*t + 1));
    }
    {   // tail chunk: only q==0, j<4 carry real k (128..131)
      uint4v a4 = {0u,0u,0u,0u};
      if (q == 0){
        a4[0] = tfpair(fbase + 128u, fbase + 129u);
        a4[1] = tfpair(fbase + 130u, fbase + 131u);
      }
      afu[4] = a4;
    }
    float racc0=0.f, racc1=0.f, racc2=0.f, racc3=0.f;
    for (int nt = 0; nt < NTIL; ++nt){
      float4v acc = {0.f,0.f,0.f,0.f};
      const short8* bp = (const short8*)&Wlds[(nt*16+col)*KSTR];
      #pragma unroll
      for (int kc = 0; kc < KCH; ++kc){
        // NOTE: bp[kc*4+q] can read past row end for kc=4,q>0 -- multiplied by
        // zero A fragment (afu[4] is 0 for q!=0), so the garbage is harmless.
        short8 bfr = bp[kc*4 + q];    // B[k][n]: n=lane&15, k=quad*8+j
        acc = __builtin_amdgcn_mfma_f32_16x16x32_bf16(
                 __builtin_bit_cast(short8, afu[kc]), bfr, acc, 0, 0, 0);
      }
      int n = nt*16 + col;            // C/D: col=lane&15, row=quad*4+reg
      float wv = wtlds[n];
      const float* cb = &clds[(q*4)*CSTR + n];
      racc0 += fmaxf(acc[0] + cb[0*CSTR], 0.f)*wv;
      racc1 += fmaxf(acc[1] + cb[1*CSTR], 0.f)*wv;
      racc2 += fmaxf(acc[2] + cb[2*CSTR], 0.f)*wv;
      racc3 += fmaxf(acc[3] + cb[3*CSTR], 0.f)*wv;
    }
    #pragma unroll
    for (int m = 1; m < 16; m <<= 1){
      racc0 += __shfl_xor(racc0, m, 64);
      racc1 += __shfl_xor(racc1, m, 64);
      racc2 += __shfl_xor(racc2, m, 64);
      racc3 += __shfl_xor(racc3, m, 64);
    }
    if (col == 0){
      part[wave*16 + q*4 + 0] = 0.02f * softplus_f(racc0);
      part[wave*16 + q*4 + 1] = 0.02f * softplus_f(racc1);
      part[wave*16 + q*4 + 2] = 0.02f * softplus_f(racc2);
      part[wave*16 + q*4 + 3] = 0.02f * softplus_f(racc3);
    }
  }
  __syncthreads();
  if (tid < 16){
    float v = 0.f;
    #pragma unroll
    for (int w = 0; w < 8; ++w) v += part[w*16 + tid];
    atomicAdd(&outmean[bl0 + tid], v);
  }
}

// ---------------- launch ----------------
extern "C" void kernel_launch(void* const* d_in, const int* in_sizes, int n_in,
                              void* d_out, int out_size, void* d_ws, size_t ws_size,
                              hipStream_t stream){
  const int*   etype = (const int*)  d_in[0];
  const float* etime = (const float*)d_in[1];
  const float* Wt    = (const float*)d_in[3];
  const float* temb  = (const float*)d_in[4];
  const float* Wg    = (const float*)d_in[5];
  const float* bgp   = (const float*)d_in[6];
  const float* Wl    = (const float*)d_in[7];
  const float* blp   = (const float*)d_in[8];
  const float* gamma = (const float*)d_in[9];
  const float* beta  = (const float*)d_in[10];
  const float* Win   = (const float*)d_in[11];
  const float* Wn    = (const float*)d_in[12];
  const float* wtm   = (const float*)d_in[13];
  const float* Wpred = (const float*)d_in[14];
  float* out = (float*)d_out;

  float*    hv     = (float*)d_ws;                    // 16384*132
  float*    sc4    = hv     + (size_t)16384*H_;       // 16384*4
  float*    hidden = sc4    + (size_t)16384*4;        // 16384*132 (cvec)
  float*    hn     = hidden + (size_t)16384*H_;       // 16384*132
  float*    rs     = hn     + (size_t)16384*H_;       // 132 (+pad)
  uint16_t* wbf    = (uint16_t*)(rs + 256);           // HPAD*KSTR bf16 image
  float*    cvec   = hidden;

  k0_embed  <<<dim3(16384),     dim3(64),  0, stream>>>(etype, etime, Wt, temb, Wg, Wl, hv, sc4, out);
  k_prep    <<<dim3(9),         dim3(256), 0, stream>>>(Wn, wbf, rs);
  k1_attn   <<<dim3(512,32),    dim3(256), 0, stream>>>(etime, sc4, hv, bgp, blp, gamma, beta, hn);
  k3_dec    <<<dim3(256),       dim3(256), 0, stream>>>(hn, Win, Wpred, cvec, out);
  k4_sampler<<<dim3(32,32,7),   dim3(512), 0, stream>>>(wbf, cvec, wtm, rs, out);
}

// Round 8
// 507.582 us; speedup vs baseline: 1.3646x; 1.1047x over previous
//
#include <hip/hip_runtime.h>
#include <stdint.h>

#define B_   32
#define L_   512
#define DT_  4
#define NT_  20
#define SMP_ 50
#define H_   132
#define HPAD 144      // 9 n-tiles of 16
#define KSTR 136      // K4 LDS k-stride (shorts)
#define CSTR 148      // K4 clds float stride
#define KCH  5        // 5 k-chunks of 32 (K padded 132 -> 160)
#define NTIL 9
#define WBF_N (HPAD*KSTR)      // 19584 shorts = 2448 uint4
#define ITILE 16      // k1 i-rows per block
#define SCSTR 520     // k1 score-row stride (shorts): 1040B, 16B-aligned, 2-way banks
#define HIDS  136     // k1 hid row stride (floats)

typedef float  float4v __attribute__((ext_vector_type(4)));
typedef short  short8  __attribute__((ext_vector_type(8)));
typedef unsigned int uint4v __attribute__((ext_vector_type(4)));

#if __has_builtin(__builtin_amdgcn_alignbit)
#define ROTL(x,r) __builtin_amdgcn_alignbit((x),(x),32u-(r))
#else
#define ROTL(x,r) (((x)<<(r))|((x)>>(32u-(r))))
#endif

// ---------------- threefry2x32, key=(0,42), JAX partitionable 32-bit path ------------
// bits[f] = o0 ^ o1 of threefry2x32((0,42), ctr=(0,f))  [verified R5-R7]
// tfpair: two independent chains (ILP-2), packed bf16 pair of 1+u in [1,2).
__device__ __forceinline__ uint32_t tfpair(uint32_t fa, uint32_t fb){
  const uint32_t ks1 = 42u;
  const uint32_t ks2 = 0x1BD11BDAu ^ 42u;
  uint32_t a0 = 0u, b0 = 0u, a1 = fa + ks1, b1 = fb + ks1;
#define TFR(r) a0+=a1; b0+=b1; a1=ROTL(a1,(r)); b1=ROTL(b1,(r)); a1^=a0; b1^=b0;
  TFR(13) TFR(15) TFR(26) TFR(6)
  a0+=ks1; a1+=ks2+1u; b0+=ks1; b1+=ks2+1u;
  TFR(17) TFR(29) TFR(16) TFR(24)
  a0+=ks2; a1+=2u;     b0+=ks2; b1+=2u;       // ks0+2
  TFR(13) TFR(15) TFR(26) TFR(6)
  a1+=ks1+3u;          b1+=ks1+3u;            // x0+=ks0 (0)
  TFR(17) TFR(29) TFR(16) TFR(24)
  a0+=ks1; a1+=ks2+4u; b0+=ks1; b1+=ks2+4u;
  TFR(13) TFR(15) TFR(26) TFR(6)
  a0+=ks2; a1+=5u;     b0+=ks2; b1+=5u;       // ks0+5
#undef TFR
  uint32_t Ya = ((a0 ^ a1) >> 9) + 0x3f808000u;   // bf16 bits in [31:16], RHU rounding
  uint32_t Yb = ((b0 ^ b1) >> 9) + 0x3f808000u;
#if __has_builtin(__builtin_amdgcn_perm)
  return __builtin_amdgcn_perm(Ya, Yb, 0x03020706u);  // {Yb.hi16, Ya.hi16}
#else
  return (Yb & 0xffff0000u) | (Ya >> 16);
#endif
}

__device__ __forceinline__ float softplus_f(float x){
  return fmaxf(x,0.f) + log1pf(expf(-fabsf(x)));
}

__device__ __forceinline__ short f2bf(float f){   // fp32 -> bf16 RNE
  uint32_t u = __float_as_uint(f);
  u += 0x7fffu + ((u>>16)&1u);
  return (short)(u>>16);
}

__device__ __forceinline__ float bf_round(float f){   // fp32 -> bf16 -> fp32
  uint32_t u = __float_as_uint(f);
  u += 0x7fffu + ((u>>16)&1u);
  u &= 0xffff0000u;
  return __uint_as_float(u);
}

// ---------------- K0: embeddings (bf16 hv image) + per-event scalars ----------------
__global__ __launch_bounds__(64) void k0_embed(
    const int* __restrict__ etype, const float* __restrict__ etime,
    const float* __restrict__ Wt,  const float* __restrict__ temb,
    const float* __restrict__ Wg,  const float* __restrict__ Wl,
    uint16_t* __restrict__ hv_bf, float* __restrict__ sc4, float* __restrict__ outmean){
  int bl = blockIdx.x;
  int l  = bl & (L_-1);
  int k  = threadIdx.x;                 // 0..63
  float t = etime[bl];
  const float M = -0.07195578414202429f;  // -ln(10000)/128
  float dterm = expf((float)(2*k) * M);
  float ang = (float)l * dterm + t * Wt[k];
  float sv, cv;
  sincosf(ang, &sv, &cv);
  hv_bf[(size_t)bl*H_ + k]      = (uint16_t)f2bf(sv);
  hv_bf[(size_t)bl*H_ + 64 + k] = (uint16_t)f2bf(cv);
  int et = etype[bl];
  if (k < 4) hv_bf[(size_t)bl*H_ + 128 + k] = (uint16_t)f2bf(temb[et*4 + k]);
  if (k == 0){
    float t0 = temb[et*4+0], t1 = temb[et*4+1], t2 = temb[et*4+2], t3 = temb[et*4+3];
    sc4[bl*4+0] = t0*Wg[0]+t1*Wg[1]+t2*Wg[2]+t3*Wg[3];  // dg  (j-side)
    sc4[bl*4+1] = t0*Wg[4]+t1*Wg[5]+t2*Wg[6]+t3*Wg[7];  // dg2 (i-side)
    sc4[bl*4+2] = t0*Wl[0]+t1*Wl[1]+t2*Wl[2]+t3*Wl[3];  // dl
    sc4[bl*4+3] = t0*Wl[4]+t1*Wl[5]+t2*Wl[6]+t3*Wl[7];  // dl2
    outmean[bl] = 0.f;   // zero accumulator for K4 atomics (out is poisoned 0xAA)
  }
}

// ---------------- K_prep: bf16(W_noise) image + rowsum fold ----------------
__global__ __launch_bounds__(256) void k_prep(const float* __restrict__ Wn,
                                              uint16_t* __restrict__ wbf,
                                              float* __restrict__ rs){
  int blk = blockIdx.x, tid = threadIdx.x;
  for (int e = tid; e < 16*KSTR; e += 256){
    int r = e / KSTR, k = e - r*KSTR;
    int n = blk*16 + r;
    uint16_t v = 0;
    if (n < H_ && k < H_) v = (uint16_t)f2bf(Wn[n*H_ + k]);
    wbf[n*KSTR + k] = v;
  }
  if (tid < 16){
    int n = blk*16 + tid;
    if (n < H_){
      float s = 0.f;
      const float* row = Wn + (size_t)n*H_;
      #pragma unroll 4
      for (int k = 0; k < H_; ++k) s += bf_round(row[k]);
      rs[n] = s;
    }
  }
}

// ---------------- K1: gated-kernel attention as MFMA flash-tile + fused LN ----------
// block: 16 i-rows; phase1 computes 16x512 score tile (fp32 -> bf16 LDS);
// phase2: scores @ hv via 16x16x32 MFMA, B-frags read from bf16 hv image (L2);
// epilogue: LayerNorm per row. Grid (L/16, B), 256 thr.
__global__ __launch_bounds__(256) void k1_attn(
    const float* __restrict__ etime, const float* __restrict__ sc4,
    const uint16_t* __restrict__ hv_bf,
    const float* __restrict__ bgp, const float* __restrict__ blp,
    const float* __restrict__ gamma, const float* __restrict__ beta,
    float* __restrict__ hn){
  __shared__ __align__(16) uint16_t scb[ITILE*SCSTR];
  __shared__ float jt[L_], jg[L_], jl[L_];
  __shared__ float rt[ITILE], rg[ITILE], rl[ITILE];
  __shared__ __align__(16) float hid[ITILE*HIDS];
  __shared__ float mur[ITILE], rsr[ITILE];
  int i0 = blockIdx.x*ITILE, b = blockIdx.y, base = b*L_;
  int tid = threadIdx.x;
  float bg = bgp[0], blv = blp[0];
  for (int j = tid; j < L_; j += 256){
    jt[j] = etime[base+j];
    jg[j] = sc4[(base+j)*4+0];
    jl[j] = sc4[(base+j)*4+2];
  }
  if (tid < ITILE){
    rt[tid] = etime[base+i0+tid];
    rg[tid] = sc4[(base+i0+tid)*4+1];
    rl[tid] = sc4[(base+i0+tid)*4+3];
  }
  __syncthreads();
  // phase 1: score tile (causal zeros exact in bf16)
  for (int e = tid; e < ITILE*L_; e += 256){
    int r = e >> 9, j = e & (L_-1);
    float v = 0.f;
    if (j < i0 + r){
      float gate = 1.f/(1.f+expf(-(jg[j] + rg[r] + bg)));
      float ls   = softplus_f(jl[j] + rl[r] + blv) + 1e-6f;
      float d    = rt[r] - jt[j];
      v = gate / (1.f + d*d/(2.f*ls*ls));
    }
    scb[r*SCSTR + j] = (uint16_t)f2bf(v);
  }
  __syncthreads();
  // phase 2: hidden[16][H] = scores @ hv  (MFMA 16x16x32)
  int wave = tid>>6, lane = tid&63, q = lane>>4, col = lane&15;
  const uint16_t* hvb = hv_bf + (size_t)base*H_;
  for (int nt = wave; nt < NTIL; nt += 4){
    float4v acc = {0.f,0.f,0.f,0.f};
    int n = nt*16 + col;
    for (int kt = 0; kt < 16; ++kt){
      short8 af = *(const short8*)&scb[col*SCSTR + kt*32 + q*8];  // A[m=col][k]
      short8 bfr = {0,0,0,0,0,0,0,0};
      if (n < H_){
        int kb = kt*32 + q*8;
        #pragma unroll
        for (int j = 0; j < 8; ++j)
          bfr[j] = (short)hvb[(size_t)(kb+j)*H_ + n];             // B[k][n]
      }
      acc = __builtin_amdgcn_mfma_f32_16x16x32_bf16(af, bfr, acc, 0, 0, 0);
    }
    if (n < H_){
      #pragma unroll
      for (int rr = 0; rr < 4; ++rr)
        hid[(q*4+rr)*HIDS + n] = acc[rr];    // C/D: row=q*4+rr, col=n
    }
  }
  __syncthreads();
  // LayerNorm: wave w handles rows 4w..4w+3
  #pragma unroll
  for (int rr = 0; rr < 4; ++rr){
    int r = wave*4 + rr;
    float x0 = hid[r*HIDS + lane];
    float x1 = hid[r*HIDS + 64 + lane];
    float x2 = (lane<4) ? hid[r*HIDS + 128 + lane] : 0.f;
    float s1 = x0+x1+x2, s2 = x0*x0+x1*x1+x2*x2;
    #pragma unroll
    for (int m=32; m; m>>=1){ s1 += __shfl_xor(s1, m, 64); s2 += __shfl_xor(s2, m, 64); }
    if (lane == 0){
      float mu = s1 * (1.f/132.f);
      float var = s2 * (1.f/132.f) - mu*mu;
      mur[r] = mu; rsr[r] = rsqrtf(var + 1e-6f);
    }
  }
  __syncthreads();
  if (tid < H_){
    float g = gamma[tid], be = beta[tid];
    #pragma unroll 4
    for (int r = 0; r < ITILE; ++r)
      hn[(size_t)(base+i0+r)*H_ + tid] = (hid[r*HIDS+tid]-mur[r])*rsr[r]*g + be;
  }
}

// ---------------- K3: decoder prep: c = hn@W_in^T ; mark_probs = softmax(hn@W_pred^T) ----------------
#define ROWS 64
__global__ __launch_bounds__(256) void k3_dec(
    const float* __restrict__ hn, const float* __restrict__ Win,
    const float* __restrict__ Wpred, float* __restrict__ cvec, float* __restrict__ outp){
  __shared__ __align__(16) float hnT[H_*ROWS];   // [k][r]
  __shared__ float logit[ROWS*NT_];
  int row0 = blockIdx.x * ROWS;
  for (int e = threadIdx.x; e < ROWS*H_; e += 256){
    int r = e / H_; int k = e - r*H_;
    hnT[k*ROWS + r] = hn[(size_t)(row0+r)*H_ + k];
  }
  __syncthreads();
  int t = threadIdx.x;
  if (t < H_+NT_){
    const float* wr = (t < H_) ? (Win + (size_t)t*H_) : (Wpred + (size_t)(t-H_)*H_);
    for (int rc = 0; rc < 4; ++rc){
      float acc[16];
      #pragma unroll
      for (int r=0;r<16;++r) acc[r]=0.f;
      for (int k = 0; k < H_; ++k){
        float w = wr[k];
        const float* hp = &hnT[k*ROWS + rc*16];
        #pragma unroll
        for (int r=0;r<16;++r) acc[r] += w * hp[r];
      }
      if (t < H_){
        #pragma unroll
        for (int r=0;r<16;++r) cvec[(size_t)(row0+rc*16+r)*H_ + t] = acc[r];
      } else {
        #pragma unroll
        for (int r=0;r<16;++r) logit[(rc*16+r)*NT_ + (t-H_)] = acc[r];
      }
    }
  }
  __syncthreads();
  if (t < ROWS){
    float mx = -1e30f;
    for (int j=0;j<NT_;++j) mx = fmaxf(mx, logit[t*NT_+j]);
    float ex[NT_]; float ssum = 0.f;
    for (int j=0;j<NT_;++j){ ex[j] = expf(logit[t*NT_+j]-mx); ssum += ex[j]; }
    float inv = 1.f/ssum;
    for (int j=0;j<NT_;++j)
      outp[(size_t)(B_*L_) + (size_t)(row0+t)*NT_ + j] = ex[j]*inv;
  }
}

// ---------------- K4: GAN sampler. 640 thr (10 waves) x z=5: exactly 50 samples ----
// LDS ~48.7KB -> 3 blocks/CU = 30 waves (94% occupancy), zero wave-slot waste.
__global__ __launch_bounds__(640, 7) void k4_sampler(
    const uint16_t* __restrict__ wbf, const float* __restrict__ cvec,
    const float* __restrict__ wt, const float* __restrict__ rs,
    float* __restrict__ outmean){
  __shared__ __align__(16) short Wlds[WBF_N];       // W_noise[n][k] bf16, zero-padded
  __shared__ __align__(16) float clds[16*CSTR];     // (c - rowsumW)[l_local][n]
  __shared__ float wtlds[HPAD];
  __shared__ float part[160];
  int tid = threadIdx.x, lane = tid & 63, wave = tid >> 6;
  int l0 = blockIdx.x*16, b = blockIdx.y, sch = blockIdx.z;
  int bl0 = b*L_ + l0;

  {   // stage W: flat 2448 x 16B vector copy (pre-converted bf16 image)
    const uint4v* g = (const uint4v*)wbf;
    uint4v* l = (uint4v*)Wlds;
    for (int idx = tid; idx < WBF_N/8; idx += 640) l[idx] = g[idx];
  }
  // stage c - rowsum(bf16(W))
  for (int m = wave; m < 16; m += 10){
    for (int n = lane; n < CSTR; n += 64){
      float v = 0.f;
      if (n < H_) v = cvec[(size_t)(bl0+m)*H_ + n] - rs[n];
      clds[m*CSTR + n] = v;
    }
  }
  if (tid < HPAD) wtlds[tid] = (tid < H_) ? wt[tid] : 0.f;
  if (tid < 160) part[tid] = 0.f;
  __syncthreads();

  int q = lane >> 4, col = lane & 15;
  int s = sch*10 + wave;            // always < 50
  {
    // A-fragments: lane holds noise[m=col][k = kc*32 + q*8 + j]  (MFMA A layout)
    uint32_t fbase = (uint32_t)(bl0 + col)*(uint32_t)(SMP_*H_)
                   + (uint32_t)s*(uint32_t)H_ + (uint32_t)(q*8);
    uint4v afu[KCH];
    #pragma unroll
    for (int kc = 0; kc < 4; ++kc){          // k <= 127 < H_: no guard
      #pragma unroll
      for (int t = 0; t < 4; ++t)
        afu[kc][t] = tfpair(fbase + (uint32_t)(kc*32 + 2*t),
                            fbase + (uint32_t)(kc*32 + 2*t + 1));
    }
    {   // tail chunk: only q==0, j<4 carry real k (128..131)
      uint4v a4 = {0u,0u,0u,0u};
      if (q == 0){
        a4[0] = tfpair(fbase + 128u, fbase + 129u);
        a4[1] = tfpair(fbase + 130u, fbase + 131u);
      }
      afu[4] = a4;
    }
    float racc0=0.f, racc1=0.f, racc2=0.f, racc3=0.f;
    for (int nt = 0; nt < NTIL; ++nt){
      float4v acc = {0.f,0.f,0.f,0.f};
      const short8* bp = (const short8*)&Wlds[(nt*16+col)*KSTR];
      #pragma unroll
      for (int kc = 0; kc < KCH; ++kc){
        // kc=4,q>0 reads past row end: multiplied by zero A fragment -- harmless
        short8 bfr = bp[kc*4 + q];    // B[k][n]: n=lane&15, k=quad*8+j
        acc = __builtin_amdgcn_mfma_f32_16x16x32_bf16(
                 __builtin_bit_cast(short8, afu[kc]), bfr, acc, 0, 0, 0);
      }
      int n = nt*16 + col;            // C/D: col=lane&15, row=quad*4+reg
      float wv = wtlds[n];
      const float* cb = &clds[(q*4)*CSTR + n];
      racc0 += fmaxf(acc[0] + cb[0*CSTR], 0.f)*wv;
      racc1 += fmaxf(acc[1] + cb[1*CSTR], 0.f)*wv;
      racc2 += fmaxf(acc[2] + cb[2*CSTR], 0.f)*wv;
      racc3 += fmaxf(acc[3] + cb[3*CSTR], 0.f)*wv;
    }
    #pragma unroll
    for (int m = 1; m < 16; m <<= 1){
      racc0 += __shfl_xor(racc0, m, 64);
      racc1 += __shfl_xor(racc1, m, 64);
      racc2 += __shfl_xor(racc2, m, 64);
      racc3 += __shfl_xor(racc3, m, 64);
    }
    if (col == 0){
      part[wave*16 + q*4 + 0] = 0.02f * softplus_f(racc0);
      part[wave*16 + q*4 + 1] = 0.02f * softplus_f(racc1);
      part[wave*16 + q*4 + 2] = 0.02f * softplus_f(racc2);
      part[wave*16 + q*4 + 3] = 0.02f * softplus_f(racc3);
    }
  }
  __syncthreads();
  if (tid < 16){
    float v = 0.f;
    #pragma unroll
    for (int w = 0; w < 10; ++w) v += part[w*16 + tid];
    atomicAdd(&outmean[bl0 + tid], v);
  }
}

// ---------------- launch ----------------
extern "C" void kernel_launch(void* const* d_in, const int* in_sizes, int n_in,
                              void* d_out, int out_size, void* d_ws, size_t ws_size,
                              hipStream_t stream){
  const int*   etype = (const int*)  d_in[0];
  const float* etime = (const float*)d_in[1];
  const float* Wt    = (const float*)d_in[3];
  const float* temb  = (const float*)d_in[4];
  const float* Wg    = (const float*)d_in[5];
  const float* bgp   = (const float*)d_in[6];
  const float* Wl    = (const float*)d_in[7];
  const float* blp   = (const float*)d_in[8];
  const float* gamma = (const float*)d_in[9];
  const float* beta  = (const float*)d_in[10];
  const float* Win   = (const float*)d_in[11];
  const float* Wn    = (const float*)d_in[12];
  const float* wtm   = (const float*)d_in[13];
  const float* Wpred = (const float*)d_in[14];
  float* out = (float*)d_out;

  uint16_t* hv_bf  = (uint16_t*)d_ws;                       // 16384*132 shorts
  float*    sc4    = (float*)(hv_bf + (size_t)16384*H_);    // 16384*4
  float*    hidden = sc4    + (size_t)16384*4;              // 16384*132 (cvec)
  float*    hn     = hidden + (size_t)16384*H_;             // 16384*132
  float*    rs     = hn     + (size_t)16384*H_;             // 132 (+pad)
  uint16_t* wbf    = (uint16_t*)(rs + 256);                 // HPAD*KSTR bf16 image
  float*    cvec   = hidden;

  k0_embed  <<<dim3(16384),     dim3(64),  0, stream>>>(etype, etime, Wt, temb, Wg, Wl, hv_bf, sc4, out);
  k_prep    <<<dim3(9),         dim3(256), 0, stream>>>(Wn, wbf, rs);
  k1_attn   <<<dim3(32,32),     dim3(256), 0, stream>>>(etime, sc4, hv_bf, bgp, blp, gamma, beta, hn);
  k3_dec    <<<dim3(256),       dim3(256), 0, stream>>>(hn, Win, Wpred, cvec, out);
  k4_sampler<<<dim3(32,32,5),   dim3(640), 0, stream>>>(wbf, cvec, wtm, rs, out);
}

// Round 9
// 430.684 us; speedup vs baseline: 1.6082x; 1.1785x over previous
//
#include <hip/hip_runtime.h>
#include <stdint.h>

#define B_   32
#define L_   512
#define DT_  4
#define NT_  20
#define SMP_ 50
#define H_   132
#define HPAD 144      // 9 n-tiles of 16 (K4 W image rows)
#define KSTR 136      // bf16 W-image k-stride (shorts)
#define CSTR 148      // K4 clds float stride
#define KCH  5        // 5 k-chunks of 32 (K padded 132 -> 160)
#define NTIL 9
#define WBF_N (HPAD*KSTR)      // 19584 shorts
#define ITILE 16      // k1 i-rows per block
#define SCSTR 520     // k1 score-row stride (shorts)
#define HIDS  136     // k1 hid row stride (floats)
#define HNSTR 160     // hn bf16 image k-stride (shorts, zero-padded 132..159)
#define WDROW 160     // [Win;Wpred] image rows (152 used)
#define NTIL3 10      // k3 n-tiles

typedef float  float4v __attribute__((ext_vector_type(4)));
typedef short  short8  __attribute__((ext_vector_type(8)));
typedef unsigned int uint4v __attribute__((ext_vector_type(4)));

#if __has_builtin(__builtin_amdgcn_alignbit)
#define ROTL(x,r) __builtin_amdgcn_alignbit((x),(x),32u-(r))
#else
#define ROTL(x,r) (((x)<<(r))|((x)>>(32u-(r))))
#endif

// ---------------- threefry2x32, key=(0,42), JAX partitionable 32-bit path ------------
// bits[f] = o0 ^ o1 of threefry2x32((0,42), ctr=(0,f))  [verified R5-R8]
__device__ __forceinline__ uint32_t tfpair(uint32_t fa, uint32_t fb){
  const uint32_t ks1 = 42u;
  const uint32_t ks2 = 0x1BD11BDAu ^ 42u;
  uint32_t a0 = 0u, b0 = 0u, a1 = fa + ks1, b1 = fb + ks1;
#define TFR(r) a0+=a1; b0+=b1; a1=ROTL(a1,(r)); b1=ROTL(b1,(r)); a1^=a0; b1^=b0;
  TFR(13) TFR(15) TFR(26) TFR(6)
  a0+=ks1; a1+=ks2+1u; b0+=ks1; b1+=ks2+1u;
  TFR(17) TFR(29) TFR(16) TFR(24)
  a0+=ks2; a1+=2u;     b0+=ks2; b1+=2u;       // ks0+2
  TFR(13) TFR(15) TFR(26) TFR(6)
  a1+=ks1+3u;          b1+=ks1+3u;            // x0+=ks0 (0)
  TFR(17) TFR(29) TFR(16) TFR(24)
  a0+=ks1; a1+=ks2+4u; b0+=ks1; b1+=ks2+4u;
  TFR(13) TFR(15) TFR(26) TFR(6)
  a0+=ks2; a1+=5u;     b0+=ks2; b1+=5u;       // ks0+5
#undef TFR
  uint32_t Ya = ((a0 ^ a1) >> 9) + 0x3f808000u;   // bf16 bits in [31:16], RHU rounding
  uint32_t Yb = ((b0 ^ b1) >> 9) + 0x3f808000u;
#if __has_builtin(__builtin_amdgcn_perm)
  return __builtin_amdgcn_perm(Ya, Yb, 0x03020706u);  // {Yb.hi16, Ya.hi16}
#else
  return (Yb & 0xffff0000u) | (Ya >> 16);
#endif
}

__device__ __forceinline__ float softplus_f(float x){
  return fmaxf(x,0.f) + log1pf(expf(-fabsf(x)));
}

__device__ __forceinline__ short f2bf(float f){   // fp32 -> bf16 RNE
  uint32_t u = __float_as_uint(f);
  u += 0x7fffu + ((u>>16)&1u);
  return (short)(u>>16);
}

__device__ __forceinline__ float bf_round(float f){   // fp32 -> bf16 -> fp32
  uint32_t u = __float_as_uint(f);
  u += 0x7fffu + ((u>>16)&1u);
  u &= 0xffff0000u;
  return __uint_as_float(u);
}

// ---------------- K0: embeddings (bf16 hv image) + per-event scalars ----------------
__global__ __launch_bounds__(64) void k0_embed(
    const int* __restrict__ etype, const float* __restrict__ etime,
    const float* __restrict__ Wt,  const float* __restrict__ temb,
    const float* __restrict__ Wg,  const float* __restrict__ Wl,
    uint16_t* __restrict__ hv_bf, float* __restrict__ sc4, float* __restrict__ outmean){
  int bl = blockIdx.x;
  int l  = bl & (L_-1);
  int k  = threadIdx.x;                 // 0..63
  float t = etime[bl];
  const float M = -0.07195578414202429f;  // -ln(10000)/128
  float dterm = expf((float)(2*k) * M);
  float ang = (float)l * dterm + t * Wt[k];
  float sv, cv;
  sincosf(ang, &sv, &cv);
  hv_bf[(size_t)bl*H_ + k]      = (uint16_t)f2bf(sv);
  hv_bf[(size_t)bl*H_ + 64 + k] = (uint16_t)f2bf(cv);
  int et = etype[bl];
  if (k < 4) hv_bf[(size_t)bl*H_ + 128 + k] = (uint16_t)f2bf(temb[et*4 + k]);
  if (k == 0){
    float t0 = temb[et*4+0], t1 = temb[et*4+1], t2 = temb[et*4+2], t3 = temb[et*4+3];
    sc4[bl*4+0] = t0*Wg[0]+t1*Wg[1]+t2*Wg[2]+t3*Wg[3];  // dg  (j-side)
    sc4[bl*4+1] = t0*Wg[4]+t1*Wg[5]+t2*Wg[6]+t3*Wg[7];  // dg2 (i-side)
    sc4[bl*4+2] = t0*Wl[0]+t1*Wl[1]+t2*Wl[2]+t3*Wl[3];  // dl
    sc4[bl*4+3] = t0*Wl[4]+t1*Wl[5]+t2*Wl[6]+t3*Wl[7];  // dl2
    outmean[bl] = 0.f;   // zero accumulator for K4 atomics (out is poisoned 0xAA)
  }
}

// ---------------- K_prep: bf16 W images. blocks 0..8: W_noise (+rowsum);
// blocks 9..18: [W_in; W_pred] rows 0..159 (152 real, rest zero) ----------------
__global__ __launch_bounds__(256) void k_prep(const float* __restrict__ Wn,
                                              const float* __restrict__ Win,
                                              const float* __restrict__ Wpred,
                                              uint16_t* __restrict__ wbf,
                                              uint16_t* __restrict__ wd,
                                              float* __restrict__ rs){
  int blk = blockIdx.x, tid = threadIdx.x;
  if (blk < 9){
    for (int e = tid; e < 16*KSTR; e += 256){
      int r = e / KSTR, k = e - r*KSTR;
      int n = blk*16 + r;
      uint16_t v = 0;
      if (n < H_ && k < H_) v = (uint16_t)f2bf(Wn[n*H_ + k]);
      wbf[n*KSTR + k] = v;
    }
    if (tid < 16){
      int n = blk*16 + tid;
      if (n < H_){
        float s = 0.f;
        const float* row = Wn + (size_t)n*H_;
        #pragma unroll 4
        for (int k = 0; k < H_; ++k) s += bf_round(row[k]);
        rs[n] = s;
      }
    }
  } else {
    int rb = blk - 9;                  // 0..9
    for (int e = tid; e < 16*KSTR; e += 256){
      int r = e / KSTR, k = e - r*KSTR;
      int n = rb*16 + r;
      uint16_t v = 0;
      if (k < H_){
        if (n < H_)            v = (uint16_t)f2bf(Win[n*H_ + k]);
        else if (n < H_+NT_)   v = (uint16_t)f2bf(Wpred[(n-H_)*H_ + k]);
      }
      wd[n*KSTR + k] = v;
    }
  }
}

// ---------------- K1: gated-kernel attention as MFMA flash-tile + fused LN ----------
// emits hn as bf16 image, stride HNSTR=160, zero-padded k=132..159.
__global__ __launch_bounds__(256) void k1_attn(
    const float* __restrict__ etime, const float* __restrict__ sc4,
    const uint16_t* __restrict__ hv_bf,
    const float* __restrict__ bgp, const float* __restrict__ blp,
    const float* __restrict__ gamma, const float* __restrict__ beta,
    uint16_t* __restrict__ hn_bf){
  __shared__ __align__(16) uint16_t scb[ITILE*SCSTR];
  __shared__ float jt[L_], jg[L_], jl[L_];
  __shared__ float rt[ITILE], rg[ITILE], rl[ITILE];
  __shared__ __align__(16) float hid[ITILE*HIDS];
  __shared__ float mur[ITILE], rsr[ITILE];
  int i0 = blockIdx.x*ITILE, b = blockIdx.y, base = b*L_;
  int tid = threadIdx.x;
  float bg = bgp[0], blv = blp[0];
  for (int j = tid; j < L_; j += 256){
    jt[j] = etime[base+j];
    jg[j] = sc4[(base+j)*4+0];
    jl[j] = sc4[(base+j)*4+2];
  }
  if (tid < ITILE){
    rt[tid] = etime[base+i0+tid];
    rg[tid] = sc4[(base+i0+tid)*4+1];
    rl[tid] = sc4[(base+i0+tid)*4+3];
  }
  __syncthreads();
  // phase 1: score tile (causal zeros exact in bf16)
  for (int e = tid; e < ITILE*L_; e += 256){
    int r = e >> 9, j = e & (L_-1);
    float v = 0.f;
    if (j < i0 + r){
      float gate = 1.f/(1.f+expf(-(jg[j] + rg[r] + bg)));
      float ls   = softplus_f(jl[j] + rl[r] + blv) + 1e-6f;
      float d    = rt[r] - jt[j];
      v = gate / (1.f + d*d/(2.f*ls*ls));
    }
    scb[r*SCSTR + j] = (uint16_t)f2bf(v);
  }
  __syncthreads();
  // phase 2: hidden[16][H] = scores @ hv  (MFMA 16x16x32)
  int wave = tid>>6, lane = tid&63, q = lane>>4, col = lane&15;
  const uint16_t* hvb = hv_bf + (size_t)base*H_;
  for (int nt = wave; nt < NTIL; nt += 4){
    float4v acc = {0.f,0.f,0.f,0.f};
    int n = nt*16 + col;
    for (int kt = 0; kt < 16; ++kt){
      short8 af = *(const short8*)&scb[col*SCSTR + kt*32 + q*8];  // A[m=col][k]
      short8 bfr = {0,0,0,0,0,0,0,0};
      if (n < H_){
        int kb = kt*32 + q*8;
        #pragma unroll
        for (int j = 0; j < 8; ++j)
          bfr[j] = (short)hvb[(size_t)(kb+j)*H_ + n];             // B[k][n]
      }
      acc = __builtin_amdgcn_mfma_f32_16x16x32_bf16(af, bfr, acc, 0, 0, 0);
    }
    if (n < H_){
      #pragma unroll
      for (int rr = 0; rr < 4; ++rr)
        hid[(q*4+rr)*HIDS + n] = acc[rr];    // C/D: row=q*4+rr, col=n
    }
  }
  __syncthreads();
  // LayerNorm stats: wave w handles rows 4w..4w+3
  #pragma unroll
  for (int rr = 0; rr < 4; ++rr){
    int r = wave*4 + rr;
    float x0 = hid[r*HIDS + lane];
    float x1 = hid[r*HIDS + 64 + lane];
    float x2 = (lane<4) ? hid[r*HIDS + 128 + lane] : 0.f;
    float s1 = x0+x1+x2, s2 = x0*x0+x1*x1+x2*x2;
    #pragma unroll
    for (int m=32; m; m>>=1){ s1 += __shfl_xor(s1, m, 64); s2 += __shfl_xor(s2, m, 64); }
    if (lane == 0){
      float mu = s1 * (1.f/132.f);
      float var = s2 * (1.f/132.f) - mu*mu;
      mur[r] = mu; rsr[r] = rsqrtf(var + 1e-6f);
    }
  }
  __syncthreads();
  if (tid < HNSTR){
    if (tid < H_){
      float g = gamma[tid], be = beta[tid];
      #pragma unroll 4
      for (int r = 0; r < ITILE; ++r)
        hn_bf[(size_t)(base+i0+r)*HNSTR + tid] =
            (uint16_t)f2bf((hid[r*HIDS+tid]-mur[r])*rsr[r]*g + be);
    } else {
      #pragma unroll 4
      for (int r = 0; r < ITILE; ++r)
        hn_bf[(size_t)(base+i0+r)*HNSTR + tid] = 0;   // zero pad k=132..159
    }
  }
}

// ---------------- K3: MFMA decoder: cvec = hn@W_in^T ; mark_probs = softmax(hn@W_pred^T)
// grid 256 blocks x 256 thr; wave w: rows blk*64 + w*16 .. +15; 10 n-tiles
// (n<132 -> cvec; 132<=n<152 -> logits -> fused softmax).
__global__ __launch_bounds__(256) void k3_dec(
    const uint16_t* __restrict__ hn_bf, const uint16_t* __restrict__ wd,
    float* __restrict__ cvec, float* __restrict__ outp){
  __shared__ float logit[64*NT_];
  int tid = threadIdx.x, wave = tid>>6, lane = tid&63, q = lane>>4, col = lane&15;
  int row0 = blockIdx.x*64;
  int r0 = row0 + wave*16;
  short8 afr[KCH];
  #pragma unroll
  for (int kc = 0; kc < KCH; ++kc)
    afr[kc] = *(const short8*)&hn_bf[(size_t)(r0+col)*HNSTR + kc*32 + q*8]; // A[m=col][k]
  for (int nt = 0; nt < NTIL3; ++nt){
    float4v acc = {0.f,0.f,0.f,0.f};
    const short8* bp = (const short8*)&wd[(nt*16+col)*KSTR];
    #pragma unroll
    for (int kc = 0; kc < KCH; ++kc){
      // kc=4,q>0 reads past row end: A is zero at k>=132 (hn pad) -- harmless
      short8 bfr = bp[kc*4 + q];     // B[n=col][k]
      acc = __builtin_amdgcn_mfma_f32_16x16x32_bf16(afr[kc], bfr, acc, 0, 0, 0);
    }
    int n = nt*16 + col;             // C/D: row=q*4+rr, col=n
    #pragma unroll
    for (int rr = 0; rr < 4; ++rr){
      int lr = wave*16 + q*4 + rr;   // local row 0..63
      if (n < H_)            cvec[(size_t)(row0+lr)*H_ + n] = acc[rr];
      else if (n < H_+NT_)   logit[lr*NT_ + (n-H_)] = acc[rr];
    }
  }
  __syncthreads();
  if (tid < 64){
    float mx = -1e30f;
    #pragma unroll
    for (int j=0;j<NT_;++j) mx = fmaxf(mx, logit[tid*NT_+j]);
    float ex[NT_]; float ssum = 0.f;
    #pragma unroll
    for (int j=0;j<NT_;++j){ ex[j] = expf(logit[tid*NT_+j]-mx); ssum += ex[j]; }
    float inv = 1.f/ssum;
    #pragma unroll
    for (int j=0;j<NT_;++j)
      outp[(size_t)(B_*L_) + (size_t)(row0+tid)*NT_ + j] = ex[j]*inv;
  }
}

// ---------------- K4: GAN sampler (R7 config: 512 thr, 8 waves, z=7) ----------------
__global__ __launch_bounds__(512, 6) void k4_sampler(
    const uint16_t* __restrict__ wbf, const float* __restrict__ cvec,
    const float* __restrict__ wt, const float* __restrict__ rs,
    float* __restrict__ outmean){
  __shared__ __align__(16) short Wlds[WBF_N];       // W_noise[n][k] bf16, zero-padded
  __shared__ __align__(16) float clds[16*CSTR];     // (c - rowsumW)[l_local][n]
  __shared__ float wtlds[HPAD];
  __shared__ float part[128];
  int tid = threadIdx.x, lane = tid & 63;
  int l0 = blockIdx.x*16, b = blockIdx.y, sch = blockIdx.z;
  int bl0 = b*L_ + l0;

  {   // stage W: flat 2448 x 16B vector copy (pre-converted bf16 image)
    const uint4v* g = (const uint4v*)wbf;
    uint4v* l = (uint4v*)Wlds;
    for (int idx = tid; idx < WBF_N/8; idx += 512) l[idx] = g[idx];
  }
  // stage c - rowsum(bf16(W))
  for (int m = tid>>6; m < 16; m += 8){
    for (int n = lane; n < CSTR; n += 64){
      float v = 0.f;
      if (n < H_) v = cvec[(size_t)(bl0+m)*H_ + n] - rs[n];
      clds[m*CSTR + n] = v;
    }
  }
  if (tid < HPAD) wtlds[tid] = (tid < H_) ? wt[tid] : 0.f;
  if (tid < 128) part[tid] = 0.f;
  __syncthreads();

  int wave = tid >> 6;
  int q = lane >> 4, col = lane & 15;
  int s = sch*8 + wave;
  if (s < SMP_){
    uint32_t fbase = (uint32_t)(bl0 + col)*(uint32_t)(SMP_*H_)
                   + (uint32_t)s*(uint32_t)H_ + (uint32_t)(q*8);
    uint4v afu[KCH];
    #pragma unroll
    for (int kc = 0; kc < 4; ++kc){          // k <= 127 < H_: no guard
      #pragma unroll
      for (int t = 0; t < 4; ++t)
        afu[kc][t] = tfpair(fbase + (uint32_t)(kc*32 + 2*t),
                            fbase + (uint32_t)(kc*32 + 2*t + 1));
    }
    {   // tail chunk: only q==0, j<4 carry real k (128..131)
      uint4v a4 = {0u,0u,0u,0u};
      if (q == 0){
        a4[0] = tfpair(fbase + 128u, fbase + 129u);
        a4[1] = tfpair(fbase + 130u, fbase + 131u);
      }
      afu[4] = a4;
    }
    float racc0=0.f, racc1=0.f, racc2=0.f, racc3=0.f;
    for (int nt = 0; nt < NTIL; ++nt){
      float4v acc = {0.f,0.f,0.f,0.f};
      const short8* bp = (const short8*)&Wlds[(nt*16+col)*KSTR];
      #pragma unroll
      for (int kc = 0; kc < KCH; ++kc){
        // kc=4,q>0 reads past row end: multiplied by zero A fragment -- harmless
        short8 bfr = bp[kc*4 + q];    // B[k][n]: n=lane&15, k=quad*8+j
        acc = __builtin_amdgcn_mfma_f32_16x16x32_bf16(
                 __builtin_bit_cast(short8, afu[kc]), bfr, acc, 0, 0, 0);
      }
      int n = nt*16 + col;            // C/D: col=lane&15, row=quad*4+reg
      float wv = wtlds[n];
      const float* cb = &clds[(q*4)*CSTR + n];
      racc0 += fmaxf(acc[0] + cb[0*CSTR], 0.f)*wv;
      racc1 += fmaxf(acc[1] + cb[1*CSTR], 0.f)*wv;
      racc2 += fmaxf(acc[2] + cb[2*CSTR], 0.f)*wv;
      racc3 += fmaxf(acc[3] + cb[3*CSTR], 0.f)*wv;
    }
    #pragma unroll
    for (int m = 1; m < 16; m <<= 1){
      racc0 += __shfl_xor(racc0, m, 64);
      racc1 += __shfl_xor(racc1, m, 64);
      racc2 += __shfl_xor(racc2, m, 64);
      racc3 += __shfl_xor(racc3, m, 64);
    }
    if (col == 0){
      part[wave*16 + q*4 + 0] = 0.02f * softplus_f(racc0);
      part[wave*16 + q*4 + 1] = 0.02f * softplus_f(racc1);
      part[wave*16 + q*4 + 2] = 0.02f * softplus_f(racc2);
      part[wave*16 + q*4 + 3] = 0.02f * softplus_f(racc3);
    }
  }
  __syncthreads();
  if (tid < 16){
    float v = 0.f;
    #pragma unroll
    for (int w = 0; w < 8; ++w) v += part[w*16 + tid];
    atomicAdd(&outmean[bl0 + tid], v);
  }
}

// ---------------- launch ----------------
extern "C" void kernel_launch(void* const* d_in, const int* in_sizes, int n_in,
                              void* d_out, int out_size, void* d_ws, size_t ws_size,
                              hipStream_t stream){
  const int*   etype = (const int*)  d_in[0];
  const float* etime = (const float*)d_in[1];
  const float* Wt    = (const float*)d_in[3];
  const float* temb  = (const float*)d_in[4];
  const float* Wg    = (const float*)d_in[5];
  const float* bgp   = (const float*)d_in[6];
  const float* Wl    = (const float*)d_in[7];
  const float* blp   = (const float*)d_in[8];
  const float* gamma = (const float*)d_in[9];
  const float* beta  = (const float*)d_in[10];
  const float* Win   = (const float*)d_in[11];
  const float* Wn    = (const float*)d_in[12];
  const float* wtm   = (const float*)d_in[13];
  const float* Wpred = (const float*)d_in[14];
  float* out = (float*)d_out;

  uint16_t* hv_bf  = (uint16_t*)d_ws;                       // 16384*132 shorts
  float*    sc4    = (float*)(hv_bf + (size_t)16384*H_);    // 16384*4 floats
  float*    cvec   = sc4    + (size_t)16384*4;              // 16384*132 floats
  float*    rs     = cvec   + (size_t)16384*H_;             // 132 (+pad to 256)
  uint16_t* hn_bf  = (uint16_t*)(rs + 256);                 // 16384*160 shorts
  uint16_t* wbf    = hn_bf  + (size_t)16384*HNSTR;          // HPAD*KSTR shorts
  uint16_t* wd     = wbf    + (size_t)WBF_N;                // WDROW*KSTR (+64 pad)

  k0_embed  <<<dim3(16384),     dim3(64),  0, stream>>>(etype, etime, Wt, temb, Wg, Wl, hv_bf, sc4, out);
  k_prep    <<<dim3(19),        dim3(256), 0, stream>>>(Wn, Win, Wpred, wbf, wd, rs);
  k1_attn   <<<dim3(32,32),     dim3(256), 0, stream>>>(etime, sc4, hv_bf, bgp, blp, gamma, beta, hn_bf);
  k3_dec    <<<dim3(256),       dim3(256), 0, stream>>>(hn_bf, wd, cvec, out);
  k4_sampler<<<dim3(32,32,7),   dim3(512), 0, stream>>>(wbf, cvec, wtm, rs, out);
}